// Round 6
// baseline (165.401 us; speedup 1.0000x reference)
//
#include <hip/hip_runtime.h>

// K=128 users, M=1024, N=C=128.
// k1 (134 MB streamed): h = h_d + A·v (complex)
//     R6: global_load_lds DMA staging (wave-private LDS buffers, no barriers).
//     Theory: VGPR-destined streaming reads are capped ~3.4 TB/s by the
//     per-CU miss-tracking budget; the LDS-DMA path + 20 waves/CU offers
//     more outstanding requests.
// k2: partial g = h @ W over 8 m-slices, float4 W loads
// k3 (tiny): reduce partials -> mag -> SINR -> atomicAdd

#define KM_ROWS (128 * 1024)

__device__ __forceinline__ float dot4(const float4& a, const float4& b) {
    return a.x*b.x + a.y*b.y + a.z*b.z + a.w*b.w;
}

template<int CTRL>
__device__ __forceinline__ float dpp_xadd(float x) {
    union { float f; int i; } u, v;
    u.f = x;
    v.i = __builtin_amdgcn_mov_dpp(u.i, CTRL, 0xf, 0xf, false);
    return x + v.f;
}

__device__ __forceinline__ float sum16(float x) {
    x = dpp_xadd<0xB1>(x);   // quad_perm xor1
    x = dpp_xadd<0x4E>(x);   // quad_perm xor2
    x = dpp_xadd<0x141>(x);  // row_half_mirror
    x = dpp_xadd<0x140>(x);  // row_mirror
    return x;
}

__global__ __launch_bounds__(256) void compute_h_kernel(
    const float* __restrict__ A_real,
    const float* __restrict__ A_imag,
    const float* __restrict__ W_v,       // row 0 = v (256 floats: v_re | v_im)
    const float* __restrict__ h_d_real,
    const float* __restrict__ h_d_imag,
    float* __restrict__ h_re,
    float* __restrict__ h_im)
{
    // per-wave 8 KB: [0..1023] = 8 rows of A_re, [1024..2047] = 8 rows of A_im
    __shared__ float lds[4][2048];

    const int lane = threadIdx.x & 63;
    const int wv   = threadIdx.x >> 6;
    const int sub  = lane & 15;          // chunk within row (16 lanes/row)
    const int rsub = lane >> 4;          // row within quad (0..3)
    const int wid  = blockIdx.x * 4 + wv;
    const int nw   = gridDim.x * 4;

    float* lre = &lds[wv][0];
    float* lim = &lds[wv][1024];

    const float4 vr0 = ((const float4*)W_v)[sub];
    const float4 vr1 = ((const float4*)W_v)[sub + 16];
    const float4 vi0 = ((const float4*)W_v)[32 + sub];
    const float4 vi1 = ((const float4*)W_v)[48 + sub];

    for (int base = wid; base < KM_ROWS / 8; base += nw) {
        const float* src_re = A_real + (size_t)base * 1024;   // 8 rows x 128
        const float* src_im = A_imag + (size_t)base * 1024;

        // 8 DMA instructions: each stages 1 KB (64 lanes x 16 B), contiguous.
        #pragma unroll
        for (int j = 0; j < 4; ++j) {
            __builtin_amdgcn_global_load_lds(
                (const __attribute__((address_space(1))) void*)(src_re + j * 256 + lane * 4),
                (__attribute__((address_space(3))) void*)(lre + j * 256),
                16, 0, 0);
        }
        #pragma unroll
        for (int j = 0; j < 4; ++j) {
            __builtin_amdgcn_global_load_lds(
                (const __attribute__((address_space(1))) void*)(src_im + j * 256 + lane * 4),
                (__attribute__((address_space(3))) void*)(lim + j * 256),
                16, 0, 0);
        }

        const int r0 = base * 8 + rsub;
        const int r1 = r0 + 4;
        const float hdr0 = h_d_real[r0], hdi0 = h_d_imag[r0];
        const float hdr1 = h_d_real[r1], hdi1 = h_d_imag[r1];

        // compiler inserts s_waitcnt vmcnt before these LDS reads
        const float4 a0 = *(const float4*)(lre + rsub * 128 + sub * 4);
        const float4 a1 = *(const float4*)(lre + rsub * 128 + 64 + sub * 4);
        const float4 c0 = *(const float4*)(lre + (4 + rsub) * 128 + sub * 4);
        const float4 c1 = *(const float4*)(lre + (4 + rsub) * 128 + 64 + sub * 4);
        const float4 b0 = *(const float4*)(lim + rsub * 128 + sub * 4);
        const float4 b1 = *(const float4*)(lim + rsub * 128 + 64 + sub * 4);
        const float4 d0 = *(const float4*)(lim + (4 + rsub) * 128 + sub * 4);
        const float4 d1 = *(const float4*)(lim + (4 + rsub) * 128 + 64 + sub * 4);

        float p_re = dot4(a0, vr0) + dot4(a1, vr1) - dot4(b0, vi0) - dot4(b1, vi1);
        float p_im = dot4(b0, vr0) + dot4(b1, vr1) + dot4(a0, vi0) + dot4(a1, vi1);
        float q_re = dot4(c0, vr0) + dot4(c1, vr1) - dot4(d0, vi0) - dot4(d1, vi1);
        float q_im = dot4(d0, vr0) + dot4(d1, vr1) + dot4(c0, vi0) + dot4(c1, vi1);

        p_re = sum16(p_re);
        p_im = sum16(p_im);
        q_re = sum16(q_re);
        q_im = sum16(q_im);

        if (sub == 0) {
            h_re[r0] = hdr0 + p_re;
            h_im[r0] = hdi0 + p_im;
            h_re[r1] = hdr1 + q_re;
            h_im[r1] = hdi1 + q_im;
        }
    }
}

__global__ __launch_bounds__(256) void gemm_partial_kernel(
    const float* __restrict__ h_re,
    const float* __restrict__ h_im,
    const float* __restrict__ W_v,       // rows 1.. = W (1024 x 256)
    float* __restrict__ part_re,         // [8][128][128] = [slice][k][c]
    float* __restrict__ part_im)
{
    const int k     = blockIdx.x >> 3;   // 0..127
    const int slice = blockIdx.x & 7;    // 0..7 (m-slice of 128)
    const int t  = threadIdx.x;          // 0..255
    const int c4 = t & 31;               // column group (4 cols each)
    const int seg = t >> 5;              // m-subrange (16 rows each)

    __shared__ float sh_re[128], sh_im[128];
    if (t < 128) {
        sh_re[t] = h_re[k * 1024 + slice * 128 + t];
        sh_im[t] = h_im[k * 1024 + slice * 128 + t];
    }
    __syncthreads();

    const float* Wb = W_v + 256 + (size_t)(slice * 128) * 256;
    float4 gre = {0.f, 0.f, 0.f, 0.f};
    float4 gim = {0.f, 0.f, 0.f, 0.f};
    const int m0 = seg * 16;
    #pragma unroll 4
    for (int m = m0; m < m0 + 16; ++m) {
        const float4* Wr4 = (const float4*)(Wb + m * 256);
        float4 wr = Wr4[c4];
        float4 wi = Wr4[c4 + 32];
        float hr = sh_re[m];
        float hi = sh_im[m];
        gre.x = fmaf(hr, wr.x, gre.x); gre.x = fmaf(-hi, wi.x, gre.x);
        gre.y = fmaf(hr, wr.y, gre.y); gre.y = fmaf(-hi, wi.y, gre.y);
        gre.z = fmaf(hr, wr.z, gre.z); gre.z = fmaf(-hi, wi.z, gre.z);
        gre.w = fmaf(hr, wr.w, gre.w); gre.w = fmaf(-hi, wi.w, gre.w);
        gim.x = fmaf(hr, wi.x, gim.x); gim.x = fmaf(hi, wr.x, gim.x);
        gim.y = fmaf(hr, wi.y, gim.y); gim.y = fmaf(hi, wr.y, gim.y);
        gim.z = fmaf(hr, wi.z, gim.z); gim.z = fmaf(hi, wr.z, gim.z);
        gim.w = fmaf(hr, wi.w, gim.w); gim.w = fmaf(hi, wr.w, gim.w);
    }

    __shared__ float4 s_re[256], s_im[256];
    s_re[t] = gre; s_im[t] = gim;
    __syncthreads();
    if (t < 32) {
        float4 r = s_re[t], i = s_im[t];
        #pragma unroll
        for (int s = 1; s < 8; ++s) {
            float4 rr = s_re[s * 32 + t], ii = s_im[s * 32 + t];
            r.x += rr.x; r.y += rr.y; r.z += rr.z; r.w += rr.w;
            i.x += ii.x; i.y += ii.y; i.z += ii.z; i.w += ii.w;
        }
        float4* pr = (float4*)(part_re + (size_t)(slice * 128 + k) * 128);
        float4* pi = (float4*)(part_im + (size_t)(slice * 128 + k) * 128);
        pr[t] = r;
        pi[t] = i;
    }
}

__global__ __launch_bounds__(128) void rate_kernel(
    const float* __restrict__ part_re,
    const float* __restrict__ part_im,
    float* __restrict__ out)
{
    const int k = blockIdx.x;    // 0..127
    const int c = threadIdx.x;   // 0..127

    float gr = 0.f, gi = 0.f;
    #pragma unroll
    for (int s = 0; s < 8; ++s) {
        gr += part_re[(s * 128 + k) * 128 + c];
        gi += part_im[(s * 128 + k) * 128 + c];
    }
    float mag = sqrtf(gr * gr + gi * gi);

    __shared__ float s_sig;
    __shared__ float s_w[2];
    if (c == k) s_sig = mag;

    float v = mag;
    #pragma unroll
    for (int off = 32; off > 0; off >>= 1) v += __shfl_xor(v, off);
    if ((c & 63) == 0) s_w[c >> 6] = v;
    __syncthreads();

    if (c == 0) {
        float total  = s_w[0] + s_w[1];
        float interf = total - s_sig;
        float R      = s_sig / (interf + 1e-11f);   // N0 = 10^(-80/10)/1000
        atomicAdd(out, -R * 1e6f);
    }
}

extern "C" void kernel_launch(void* const* d_in, const int* in_sizes, int n_in,
                              void* d_out, int out_size, void* d_ws, size_t ws_size,
                              hipStream_t stream) {
    const float* W_v      = (const float*)d_in[0];
    const float* A_real   = (const float*)d_in[1];
    const float* A_imag   = (const float*)d_in[2];
    const float* h_d_real = (const float*)d_in[3];
    const float* h_d_imag = (const float*)d_in[4];
    float* out  = (float*)d_out;

    float* h_re    = (float*)d_ws;          // 131072 floats
    float* h_im    = h_re + KM_ROWS;        // 131072 floats
    float* part_re = h_im + KM_ROWS;        // 8*128*128 = 131072 floats
    float* part_im = part_re + 8 * 128 * 128;

    hipMemsetAsync(d_out, 0, sizeof(float), stream);

    // 2048 blocks x 4 waves = 8192 waves; 8 rows/wave/iter; 2 iters each
    compute_h_kernel<<<2048, 256, 0, stream>>>(A_real, A_imag, W_v,
                                               h_d_real, h_d_imag, h_re, h_im);
    gemm_partial_kernel<<<1024, 256, 0, stream>>>(h_re, h_im, W_v, part_re, part_im);
    rate_kernel<<<128, 128, 0, stream>>>(part_re, part_im, out);
}

// Round 7
// 157.157 us; speedup vs baseline: 1.0525x; 1.0525x over previous
//
#include <hip/hip_runtime.h>

// K=128 users, M=1024, N=C=128.
// k1 (134 MB streamed, at ~3.4 TB/s device read ceiling): h = h_d + A·v
//     Best-measured variant (R5): non-temporal dwordx4 loads, DPP sum16,
//     one 8-row tile per wave (no loop).
// k2: partial g = h @ W over 8 m-slices; 2 users/block share W reads.
// k3 (tiny): reduce partials -> mag -> SINR -> atomicAdd

#define KM_ROWS (128 * 1024)

typedef float vf4 __attribute__((ext_vector_type(4)));

__device__ __forceinline__ float dot4v(vf4 a, const float4& b) {
    return a.x*b.x + a.y*b.y + a.z*b.z + a.w*b.w;
}

template<int CTRL>
__device__ __forceinline__ float dpp_xadd(float x) {
    union { float f; int i; } u, v;
    u.f = x;
    v.i = __builtin_amdgcn_mov_dpp(u.i, CTRL, 0xf, 0xf, false);
    return x + v.f;
}

__device__ __forceinline__ float sum16(float x) {
    x = dpp_xadd<0xB1>(x);   // quad_perm xor1
    x = dpp_xadd<0x4E>(x);   // quad_perm xor2
    x = dpp_xadd<0x141>(x);  // row_half_mirror
    x = dpp_xadd<0x140>(x);  // row_mirror
    return x;
}

__global__ __launch_bounds__(256) void compute_h_kernel(
    const float* __restrict__ A_real,
    const float* __restrict__ A_imag,
    const float* __restrict__ W_v,       // row 0 = v (256 floats: v_re | v_im)
    const float* __restrict__ h_d_real,
    const float* __restrict__ h_d_imag,
    float* __restrict__ h_re,
    float* __restrict__ h_im)
{
    const int lane = threadIdx.x & 63;
    const int sub  = lane & 15;          // chunk within row (16 lanes/row)
    const int rsub = lane >> 4;          // row within quad (0..3)
    const int base = blockIdx.x * 4 + (threadIdx.x >> 6);  // one 8-row tile/wave

    const float4 vr0 = ((const float4*)W_v)[sub];
    const float4 vr1 = ((const float4*)W_v)[sub + 16];
    const float4 vi0 = ((const float4*)W_v)[32 + sub];
    const float4 vi1 = ((const float4*)W_v)[48 + sub];

    const int r0 = base * 8 + rsub;
    const int r1 = r0 + 4;
    const vf4* Ar0 = (const vf4*)(A_real + (size_t)r0 * 128);
    const vf4* Ai0 = (const vf4*)(A_imag + (size_t)r0 * 128);
    const vf4* Ar1 = (const vf4*)(A_real + (size_t)r1 * 128);
    const vf4* Ai1 = (const vf4*)(A_imag + (size_t)r1 * 128);

    // non-temporal: skip L1 allocation for the single-use stream
    const vf4 a0 = __builtin_nontemporal_load(Ar0 + sub);
    const vf4 a1 = __builtin_nontemporal_load(Ar0 + sub + 16);
    const vf4 b0 = __builtin_nontemporal_load(Ai0 + sub);
    const vf4 b1 = __builtin_nontemporal_load(Ai0 + sub + 16);
    const vf4 c0 = __builtin_nontemporal_load(Ar1 + sub);
    const vf4 c1 = __builtin_nontemporal_load(Ar1 + sub + 16);
    const vf4 d0 = __builtin_nontemporal_load(Ai1 + sub);
    const vf4 d1 = __builtin_nontemporal_load(Ai1 + sub + 16);

    const float hdr0 = h_d_real[r0], hdi0 = h_d_imag[r0];
    const float hdr1 = h_d_real[r1], hdi1 = h_d_imag[r1];

    float p_re = dot4v(a0, vr0) + dot4v(a1, vr1) - dot4v(b0, vi0) - dot4v(b1, vi1);
    float p_im = dot4v(b0, vr0) + dot4v(b1, vr1) + dot4v(a0, vi0) + dot4v(a1, vi1);
    float q_re = dot4v(c0, vr0) + dot4v(c1, vr1) - dot4v(d0, vi0) - dot4v(d1, vi1);
    float q_im = dot4v(d0, vr0) + dot4v(d1, vr1) + dot4v(c0, vi0) + dot4v(c1, vi1);

    p_re = sum16(p_re);
    p_im = sum16(p_im);
    q_re = sum16(q_re);
    q_im = sum16(q_im);

    if (sub == 0) {
        h_re[r0] = hdr0 + p_re;
        h_im[r0] = hdi0 + p_im;
        h_re[r1] = hdr1 + q_re;
        h_im[r1] = hdi1 + q_im;
    }
}

__global__ __launch_bounds__(256) void gemm_partial_kernel(
    const float* __restrict__ h_re,
    const float* __restrict__ h_im,
    const float* __restrict__ W_v,       // rows 1.. = W (1024 x 256)
    float* __restrict__ part_re,         // [8][128][128] = [slice][k][c]
    float* __restrict__ part_im,
    float* __restrict__ out)             // zero-init by block 0
{
    const int kp    = blockIdx.x >> 3;   // 0..63 -> users kp and kp+64
    const int slice = blockIdx.x & 7;    // 0..7 (m-slice of 128)
    const int t  = threadIdx.x;          // 0..255
    const int c4 = t & 31;               // column group (4 cols each)
    const int seg = t >> 5;              // m-subrange (16 rows each)

    if (blockIdx.x == 0 && t == 0) *out = 0.f;   // replaces memset dispatch

    const int k0 = kp, k1 = kp + 64;

    __shared__ float sh_re[2][128], sh_im[2][128];
    if (t < 128) {
        sh_re[0][t] = h_re[k0 * 1024 + slice * 128 + t];
        sh_im[0][t] = h_im[k0 * 1024 + slice * 128 + t];
    } else {
        sh_re[1][t - 128] = h_re[k1 * 1024 + slice * 128 + (t - 128)];
        sh_im[1][t - 128] = h_im[k1 * 1024 + slice * 128 + (t - 128)];
    }
    __syncthreads();

    const float* Wb = W_v + 256 + (size_t)(slice * 128) * 256;
    float4 gre0 = {0,0,0,0}, gim0 = {0,0,0,0};
    float4 gre1 = {0,0,0,0}, gim1 = {0,0,0,0};
    const int m0 = seg * 16;
    #pragma unroll 4
    for (int m = m0; m < m0 + 16; ++m) {
        const float4* Wr4 = (const float4*)(Wb + m * 256);
        float4 wr = Wr4[c4];
        float4 wi = Wr4[c4 + 32];
        float hr0 = sh_re[0][m], hi0 = sh_im[0][m];
        float hr1 = sh_re[1][m], hi1 = sh_im[1][m];
        gre0.x = fmaf(hr0, wr.x, fmaf(-hi0, wi.x, gre0.x));
        gre0.y = fmaf(hr0, wr.y, fmaf(-hi0, wi.y, gre0.y));
        gre0.z = fmaf(hr0, wr.z, fmaf(-hi0, wi.z, gre0.z));
        gre0.w = fmaf(hr0, wr.w, fmaf(-hi0, wi.w, gre0.w));
        gim0.x = fmaf(hr0, wi.x, fmaf(hi0, wr.x, gim0.x));
        gim0.y = fmaf(hr0, wi.y, fmaf(hi0, wr.y, gim0.y));
        gim0.z = fmaf(hr0, wi.z, fmaf(hi0, wr.z, gim0.z));
        gim0.w = fmaf(hr0, wi.w, fmaf(hi0, wr.w, gim0.w));
        gre1.x = fmaf(hr1, wr.x, fmaf(-hi1, wi.x, gre1.x));
        gre1.y = fmaf(hr1, wr.y, fmaf(-hi1, wi.y, gre1.y));
        gre1.z = fmaf(hr1, wr.z, fmaf(-hi1, wi.z, gre1.z));
        gre1.w = fmaf(hr1, wr.w, fmaf(-hi1, wi.w, gre1.w));
        gim1.x = fmaf(hr1, wi.x, fmaf(hi1, wr.x, gim1.x));
        gim1.y = fmaf(hr1, wi.y, fmaf(hi1, wr.y, gim1.y));
        gim1.z = fmaf(hr1, wi.z, fmaf(hi1, wr.z, gim1.z));
        gim1.w = fmaf(hr1, wi.w, fmaf(hi1, wr.w, gim1.w));
    }

    __shared__ float4 s_re[2][256], s_im[2][256];
    s_re[0][t] = gre0; s_im[0][t] = gim0;
    s_re[1][t] = gre1; s_im[1][t] = gim1;
    __syncthreads();
    if (t < 64) {
        const int u  = t >> 5;          // user half (0 -> k0, 1 -> k1)
        const int cg = t & 31;          // column group
        float4 r = s_re[u][cg], i = s_im[u][cg];
        #pragma unroll
        for (int s = 1; s < 8; ++s) {
            float4 rr = s_re[u][s * 32 + cg], ii = s_im[u][s * 32 + cg];
            r.x += rr.x; r.y += rr.y; r.z += rr.z; r.w += rr.w;
            i.x += ii.x; i.y += ii.y; i.z += ii.z; i.w += ii.w;
        }
        const int k = (u == 0) ? k0 : k1;
        float4* pr = (float4*)(part_re + (size_t)(slice * 128 + k) * 128);
        float4* pi = (float4*)(part_im + (size_t)(slice * 128 + k) * 128);
        pr[cg] = r;
        pi[cg] = i;
    }
}

__global__ __launch_bounds__(128) void rate_kernel(
    const float* __restrict__ part_re,
    const float* __restrict__ part_im,
    float* __restrict__ out)
{
    const int k = blockIdx.x;    // 0..127
    const int c = threadIdx.x;   // 0..127

    float gr = 0.f, gi = 0.f;
    #pragma unroll
    for (int s = 0; s < 8; ++s) {
        gr += part_re[(s * 128 + k) * 128 + c];
        gi += part_im[(s * 128 + k) * 128 + c];
    }
    float mag = sqrtf(gr * gr + gi * gi);

    __shared__ float s_sig;
    __shared__ float s_w[2];
    if (c == k) s_sig = mag;

    float v = mag;
    #pragma unroll
    for (int off = 32; off > 0; off >>= 1) v += __shfl_xor(v, off);
    if ((c & 63) == 0) s_w[c >> 6] = v;
    __syncthreads();

    if (c == 0) {
        float total  = s_w[0] + s_w[1];
        float interf = total - s_sig;
        float R      = s_sig / (interf + 1e-11f);   // N0 = 10^(-80/10)/1000
        atomicAdd(out, -R * 1e6f);
    }
}

extern "C" void kernel_launch(void* const* d_in, const int* in_sizes, int n_in,
                              void* d_out, int out_size, void* d_ws, size_t ws_size,
                              hipStream_t stream) {
    const float* W_v      = (const float*)d_in[0];
    const float* A_real   = (const float*)d_in[1];
    const float* A_imag   = (const float*)d_in[2];
    const float* h_d_real = (const float*)d_in[3];
    const float* h_d_imag = (const float*)d_in[4];
    float* out  = (float*)d_out;

    float* h_re    = (float*)d_ws;          // 131072 floats
    float* h_im    = h_re + KM_ROWS;        // 131072 floats
    float* part_re = h_im + KM_ROWS;        // 8*128*128 = 131072 floats
    float* part_im = part_re + 8 * 128 * 128;

    // 4096 blocks x 4 waves = 16384 waves; one 8-row tile per wave
    compute_h_kernel<<<4096, 256, 0, stream>>>(A_real, A_imag, W_v,
                                               h_d_real, h_d_imag, h_re, h_im);
    // 64 user-pairs x 8 m-slices = 512 blocks (W reads shared by 2 users)
    gemm_partial_kernel<<<512, 256, 0, stream>>>(h_re, h_im, W_v,
                                                 part_re, part_im, out);
    rate_kernel<<<128, 128, 0, stream>>>(part_re, part_im, out);
}